// Round 1
// baseline (579.818 us; speedup 1.0000x reference)
//
#include <hip/hip_runtime.h>
#include <hip/hip_bf16.h>
#include <stdint.h>

#define S_LEN 2048
#define NH    16
#define DH    64
#define D_EMB 1024

typedef __attribute__((ext_vector_type(8))) short short8;
typedef __attribute__((ext_vector_type(4))) float f32x4;

__device__ __forceinline__ unsigned short f2bf(float f) {
  uint32_t u = __builtin_bit_cast(uint32_t, f);
  uint32_t r = (u + 0x7FFFu + ((u >> 16) & 1u)) >> 16;
  return (unsigned short)r;
}

__device__ __forceinline__ void gload16(const void* g, void* l) {
  __builtin_amdgcn_global_load_lds(
      (__attribute__((address_space(1))) void*)(g),
      (__attribute__((address_space(3))) void*)(l),
      16, 0, 0);
}

// ---------------- converters ----------------

__global__ __launch_bounds__(256)
void cvt_bf16(const float* __restrict__ in, unsigned short* __restrict__ out, int n) {
  int i = (blockIdx.x * 256 + threadIdx.x) * 4;
  if (i >= n) return;
  float4 v = *(const float4*)&in[i];
  ushort4 o;
  o.x = f2bf(v.x); o.y = f2bf(v.y); o.z = f2bf(v.z); o.w = f2bf(v.w);
  *(ushort4*)&out[i] = o;
}

// in: [R][C] fp32  ->  out: [C][R] bf16
__global__ __launch_bounds__(256)
void transpose_cvt(const float* __restrict__ in, unsigned short* __restrict__ out,
                   int R, int C) {
  __shared__ float t[64][65];
  const int nbr = R >> 6;
  const int br = (blockIdx.x % nbr) << 6;
  const int bc = (blockIdx.x / nbr) << 6;
  const int tid = threadIdx.x;
  const int tr = tid >> 4;          // 0..15
  const int tc = (tid & 15) << 2;   // 0,4,..,60
#pragma unroll
  for (int i = 0; i < 4; ++i) {
    float4 v = *(const float4*)&in[(size_t)(br + tr + i * 16) * C + bc + tc];
    t[tr + i * 16][tc + 0] = v.x;
    t[tr + i * 16][tc + 1] = v.y;
    t[tr + i * 16][tc + 2] = v.z;
    t[tr + i * 16][tc + 3] = v.w;
  }
  __syncthreads();
#pragma unroll
  for (int i = 0; i < 4; ++i) {
    int c = tr + i * 16;
    ushort4 o;
    o.x = f2bf(t[tc + 0][c]);
    o.y = f2bf(t[tc + 1][c]);
    o.z = f2bf(t[tc + 2][c]);
    o.w = f2bf(t[tc + 3][c]);
    *(ushort4*)&out[(size_t)(bc + c) * R + br + tc] = o;
  }
}

// ---------------- GEMM (A[M][K] bf16 x Bt[N][K] bf16) ----------------
// MODE 0: epilogue + b_in, route to Q [BH][S][64], K [BH][S][64], Vt [BH][64][S]
// MODE 1: epilogue + b_out, fp32 out [M][N]

template <int MODE>
__global__ __launch_bounds__(256, 2)
void gemm_bt(const unsigned short* __restrict__ A,
             const unsigned short* __restrict__ Bt,
             const float* __restrict__ bias,
             unsigned short* __restrict__ q_out,
             unsigned short* __restrict__ k_out,
             unsigned short* __restrict__ vt_out,
             float* __restrict__ f_out,
             int M, int N, int K) {
  __shared__ __attribute__((aligned(16))) unsigned short As[128 * 64];
  __shared__ __attribute__((aligned(16))) unsigned short Bs[128 * 64];
  const int tid  = threadIdx.x;
  const int lane = tid & 63;
  const int w    = tid >> 6;
  const int grp  = lane >> 4;
  const int lc   = lane & 15;
  const int nbn  = N >> 7;
  const int bm   = blockIdx.x / nbn;
  const int bn   = blockIdx.x % nbn;
  const int wr   = w >> 1, wc = w & 1;

  f32x4 acc[4][4];
#pragma unroll
  for (int m = 0; m < 4; ++m)
#pragma unroll
    for (int n = 0; n < 4; ++n) acc[m][n] = f32x4{0.f, 0.f, 0.f, 0.f};

  const int srow = lane >> 3;        // 0..7
  const int scol = (lane & 7) * 8;   // element col within 64
  const int nkt  = K >> 6;

  for (int kt = 0; kt < nkt; ++kt) {
#pragma unroll
    for (int c = 0; c < 4; ++c) {
      int rc = (w * 4 + c) * 8;
      gload16(&A[(size_t)(bm * 128 + rc + srow) * K + kt * 64 + scol],
              (void*)(As + rc * 64));
      gload16(&Bt[(size_t)(bn * 128 + rc + srow) * K + kt * 64 + scol],
              (void*)(Bs + rc * 64));
    }
    __syncthreads();
#pragma unroll
    for (int kk = 0; kk < 2; ++kk) {
      short8 af[4], bf[4];
#pragma unroll
      for (int m = 0; m < 4; ++m)
        af[m] = *(const short8*)(As + (wr * 64 + m * 16 + lc) * 64 + kk * 32 + grp * 8);
#pragma unroll
      for (int n = 0; n < 4; ++n)
        bf[n] = *(const short8*)(Bs + (wc * 64 + n * 16 + lc) * 64 + kk * 32 + grp * 8);
#pragma unroll
      for (int m = 0; m < 4; ++m)
#pragma unroll
        for (int n = 0; n < 4; ++n)
          acc[m][n] = __builtin_amdgcn_mfma_f32_16x16x32_bf16(af[m], bf[n], acc[m][n], 0, 0, 0);
    }
    __syncthreads();
  }

  const int gm0 = bm * 128 + wr * 64;
  const int gn0 = bn * 128 + wc * 64;
  if (MODE == 0) {
    const int seg = gn0 >> 10;  // 0=Q, 1=K, 2=V (128-col block never straddles)
#pragma unroll
    for (int m = 0; m < 4; ++m) {
#pragma unroll
      for (int n = 0; n < 4; ++n) {
        const int gn = gn0 + n * 16 + lc;
        const float bv = bias[gn];
        const int j = gn & 1023;
        const int h = j >> 6, d = j & 63;
#pragma unroll
        for (int r = 0; r < 4; ++r) {
          const int gm = gm0 + m * 16 + grp * 4 + r;
          const int b = gm >> 11, s = gm & 2047;
          const unsigned short val = f2bf(acc[m][n][r] + bv);
          if (seg == 0)
            q_out[(((size_t)(b * NH + h)) * S_LEN + s) * DH + d] = val;
          else if (seg == 1)
            k_out[(((size_t)(b * NH + h)) * S_LEN + s) * DH + d] = val;
          else
            vt_out[(((size_t)(b * NH + h)) * DH + d) * S_LEN + s] = val;
        }
      }
    }
  } else {
#pragma unroll
    for (int m = 0; m < 4; ++m) {
#pragma unroll
      for (int n = 0; n < 4; ++n) {
        const int gn = gn0 + n * 16 + lc;
        const float bv = bias[gn];
#pragma unroll
        for (int r = 0; r < 4; ++r) {
          const int gm = gm0 + m * 16 + grp * 4 + r;
          f_out[(size_t)gm * N + gn] = acc[m][n][r] + bv;
        }
      }
    }
  }
}

// ---------------- flash attention (causal) ----------------
// Q,K: [BH][S][64] bf16; Vt: [BH][64][S] bf16; Aout: [B*S][1024] bf16

#define CSCALE 0.18033688011112042f  // 0.125 * log2(e)

__global__ __launch_bounds__(256, 2)
void attn_fwd(const unsigned short* __restrict__ Q,
              const unsigned short* __restrict__ K,
              const unsigned short* __restrict__ Vt,
              unsigned short* __restrict__ Aout) {
  __shared__ __attribute__((aligned(16))) unsigned short Pl[4][16][32];
  const int tid = threadIdx.x;
  const int lane = tid & 63, w = tid >> 6;
  const int grp = lane >> 4, lc = lane & 15;
  const int qb = blockIdx.x & 31;   // S/64
  const int bh = blockIdx.x >> 5;   // b*16+h
  const int q0 = qb * 64;
  const int qw0 = q0 + w * 16;

  const size_t kq_base = (size_t)bh * S_LEN * DH;
  const size_t vt_base = (size_t)bh * DH * S_LEN;

  short8 qf[2];
#pragma unroll
  for (int kh = 0; kh < 2; ++kh)
    qf[kh] = *(const short8*)(Q + kq_base + (size_t)(qw0 + lc) * DH + kh * 32 + grp * 8);

  f32x4 oacc[4];
#pragma unroll
  for (int dt = 0; dt < 4; ++dt) oacc[dt] = f32x4{0.f, 0.f, 0.f, 0.f};
  float mrow[4] = {-1e30f, -1e30f, -1e30f, -1e30f};
  float lrow[4] = {0.f, 0.f, 0.f, 0.f};

  const int nkv = (qw0 + 47) >> 5;
  for (int kv = 0; kv < nkv; ++kv) {
    const int kvb = kv * 32;
    f32x4 sacc[2];
#pragma unroll
    for (int ct = 0; ct < 2; ++ct) {
      short8 kf0 = *(const short8*)(K + kq_base + (size_t)(kvb + ct * 16 + lc) * DH + grp * 8);
      short8 kf1 = *(const short8*)(K + kq_base + (size_t)(kvb + ct * 16 + lc) * DH + 32 + grp * 8);
      f32x4 z = f32x4{0.f, 0.f, 0.f, 0.f};
      z = __builtin_amdgcn_mfma_f32_16x16x32_bf16(qf[0], kf0, z, 0, 0, 0);
      sacc[ct] = __builtin_amdgcn_mfma_f32_16x16x32_bf16(qf[1], kf1, z, 0, 0, 0);
    }
    if (kvb + 31 > qw0) {
#pragma unroll
      for (int ct = 0; ct < 2; ++ct)
#pragma unroll
        for (int r = 0; r < 4; ++r)
          if (kvb + ct * 16 + lc > qw0 + grp * 4 + r) sacc[ct][r] = -1e30f;
    }
#pragma unroll
    for (int r = 0; r < 4; ++r) {
      float mx = fmaxf(sacc[0][r], sacc[1][r]);
      mx = fmaxf(mx, __shfl_xor(mx, 1));
      mx = fmaxf(mx, __shfl_xor(mx, 2));
      mx = fmaxf(mx, __shfl_xor(mx, 4));
      mx = fmaxf(mx, __shfl_xor(mx, 8));
      const float mnew = fmaxf(mrow[r], mx);
      const float so = exp2f((mrow[r] - mnew) * CSCALE);
      const float p0 = exp2f((sacc[0][r] - mnew) * CSCALE);
      const float p1 = exp2f((sacc[1][r] - mnew) * CSCALE);
      float ps = p0 + p1;
      ps += __shfl_xor(ps, 1);
      ps += __shfl_xor(ps, 2);
      ps += __shfl_xor(ps, 4);
      ps += __shfl_xor(ps, 8);
      lrow[r] = lrow[r] * so + ps;
      mrow[r] = mnew;
#pragma unroll
      for (int dt = 0; dt < 4; ++dt) oacc[dt][r] *= so;
      Pl[w][grp * 4 + r][lc] = f2bf(p0);
      Pl[w][grp * 4 + r][16 + lc] = f2bf(p1);
    }
    short8 pa = *(const short8*)&Pl[w][lc][grp * 8];
#pragma unroll
    for (int dt = 0; dt < 4; ++dt) {
      short8 vf = *(const short8*)(Vt + vt_base + (size_t)(dt * 16 + lc) * S_LEN + kvb + grp * 8);
      oacc[dt] = __builtin_amdgcn_mfma_f32_16x16x32_bf16(pa, vf, oacc[dt], 0, 0, 0);
    }
  }

  const int b = bh >> 4, h = bh & 15;
#pragma unroll
  for (int r = 0; r < 4; ++r) {
    const float inv = 1.0f / lrow[r];
    const int s = qw0 + grp * 4 + r;
    const size_t rowbase = ((size_t)(b * S_LEN + s)) * D_EMB + h * DH;
#pragma unroll
    for (int dt = 0; dt < 4; ++dt)
      Aout[rowbase + dt * 16 + lc] = f2bf(oacc[dt][r] * inv);
  }
}

// ---------------- launcher ----------------

extern "C" void kernel_launch(void* const* d_in, const int* in_sizes, int n_in,
                              void* d_out, int out_size, void* d_ws, size_t ws_size,
                              hipStream_t stream) {
  const float* x     = (const float*)d_in[0];
  const float* W_in  = (const float*)d_in[1];
  const float* b_in  = (const float*)d_in[2];
  const float* W_out = (const float*)d_in[3];
  const float* b_out = (const float*)d_in[4];

  char* ws = (char*)d_ws;
  unsigned short* xb  = (unsigned short*)(ws);              // 16 MB: x bf16, later attn_out
  unsigned short* Wti = (unsigned short*)(ws + 16777216);   // 6 MB: W_in^T bf16 [3072][1024]
  unsigned short* Wto = (unsigned short*)(ws + 23068672);   // 2 MB: W_out^T bf16 [1024][1024]
  unsigned short* Qb  = (unsigned short*)(ws + 25165824);   // 16 MB [64][2048][64]
  unsigned short* Kb  = (unsigned short*)(ws + 41943040);   // 16 MB [64][2048][64]
  unsigned short* Vtb = (unsigned short*)(ws + 58720256);   // 16 MB [64][64][2048]
  float* out = (float*)d_out;

  cvt_bf16<<<8192, 256, 0, stream>>>(x, xb, 8388608);
  transpose_cvt<<<16 * 48, 256, 0, stream>>>(W_in, Wti, 1024, 3072);
  transpose_cvt<<<16 * 16, 256, 0, stream>>>(W_out, Wto, 1024, 1024);

  // QKV projection: M=8192, N=3072, K=1024
  gemm_bt<0><<<64 * 24, 256, 0, stream>>>(xb, Wti, b_in, Qb, Kb, Vtb, nullptr,
                                          8192, 3072, 1024);
  // causal flash attention -> xb reused as attn_out [8192][1024] bf16
  attn_fwd<<<64 * 32, 256, 0, stream>>>(Qb, Kb, Vtb, xb);
  // output projection: M=8192, N=1024, K=1024 -> fp32 + b_out
  gemm_bt<1><<<64 * 8, 256, 0, stream>>>(xb, Wto, b_out, nullptr, nullptr, nullptr, out,
                                         8192, 1024, 1024);
}

// Round 3
// 259.630 us; speedup vs baseline: 2.2333x; 2.2333x over previous
//
#include <hip/hip_runtime.h>
#include <hip/hip_bf16.h>
#include <stdint.h>

#define S_LEN 2048
#define NH    16
#define DH    64
#define D_EMB 1024

typedef __attribute__((ext_vector_type(8)))  short short8;
typedef __attribute__((ext_vector_type(4)))  float f32x4;
typedef __attribute__((ext_vector_type(16))) float f32x16;

__device__ __forceinline__ unsigned short f2bf(float f) {
  uint32_t u = __builtin_bit_cast(uint32_t, f);
  uint32_t r = (u + 0x7FFFu + ((u >> 16) & 1u)) >> 16;
  return (unsigned short)r;
}

__device__ __forceinline__ void gload16(const void* g, void* l) {
  __builtin_amdgcn_global_load_lds(
      (__attribute__((address_space(1))) void*)(g),
      (__attribute__((address_space(3))) void*)(l),
      16, 0, 0);
}

__device__ __forceinline__ f32x16 mfma32(short8 a, short8 b, f32x16 c) {
  return __builtin_amdgcn_mfma_f32_32x32x16_bf16(a, b, c, 0, 0, 0);
}

// ---------------- converters ----------------

__global__ __launch_bounds__(256)
void cvt_bf16(const float* __restrict__ in, unsigned short* __restrict__ out, int n) {
  int i = (blockIdx.x * 256 + threadIdx.x) * 4;
  if (i >= n) return;
  float4 v = *(const float4*)&in[i];
  ushort4 o;
  o.x = f2bf(v.x); o.y = f2bf(v.y); o.z = f2bf(v.z); o.w = f2bf(v.w);
  *(ushort4*)&out[i] = o;
}

// in: [R][C] fp32  ->  out: [C][R] bf16
__global__ __launch_bounds__(256)
void transpose_cvt(const float* __restrict__ in, unsigned short* __restrict__ out,
                   int R, int C) {
  __shared__ float t[64][65];
  const int nbr = R >> 6;
  const int br = (blockIdx.x % nbr) << 6;
  const int bc = (blockIdx.x / nbr) << 6;
  const int tid = threadIdx.x;
  const int tr = tid >> 4;
  const int tc = (tid & 15) << 2;
#pragma unroll
  for (int i = 0; i < 4; ++i) {
    float4 v = *(const float4*)&in[(size_t)(br + tr + i * 16) * C + bc + tc];
    t[tr + i * 16][tc + 0] = v.x;
    t[tr + i * 16][tc + 1] = v.y;
    t[tr + i * 16][tc + 2] = v.z;
    t[tr + i * 16][tc + 3] = v.w;
  }
  __syncthreads();
#pragma unroll
  for (int i = 0; i < 4; ++i) {
    int c = tr + i * 16;
    ushort4 o;
    o.x = f2bf(t[tc + 0][c]);
    o.y = f2bf(t[tc + 1][c]);
    o.z = f2bf(t[tc + 2][c]);
    o.w = f2bf(t[tc + 3][c]);
    *(ushort4*)&out[(size_t)(bc + c) * R + br + tc] = o;
  }
}

// ---------------- GEMM (A[M][K] bf16 x Bt[N][K] bf16) ----------------

template <int MODE>
__global__ __launch_bounds__(256, 2)
void gemm_bt(const unsigned short* __restrict__ A,
             const unsigned short* __restrict__ Bt,
             const float* __restrict__ bias,
             unsigned short* __restrict__ q_out,
             unsigned short* __restrict__ k_out,
             unsigned short* __restrict__ vt_out,
             float* __restrict__ f_out,
             int M, int N, int K) {
  __shared__ __attribute__((aligned(16))) unsigned short As[128 * 64];
  __shared__ __attribute__((aligned(16))) unsigned short Bs[128 * 64];
  const int tid  = threadIdx.x;
  const int lane = tid & 63;
  const int w    = tid >> 6;
  const int grp  = lane >> 4;
  const int lc   = lane & 15;
  const int nbn  = N >> 7;
  const int bm   = blockIdx.x / nbn;
  const int bn   = blockIdx.x % nbn;
  const int wr   = w >> 1, wc = w & 1;

  f32x4 acc[4][4];
#pragma unroll
  for (int m = 0; m < 4; ++m)
#pragma unroll
    for (int n = 0; n < 4; ++n) acc[m][n] = f32x4{0.f, 0.f, 0.f, 0.f};

  const int srow = lane >> 3;
  const int scol = (lane & 7) * 8;
  const int nkt  = K >> 6;

  for (int kt = 0; kt < nkt; ++kt) {
#pragma unroll
    for (int c = 0; c < 4; ++c) {
      int rc = (w * 4 + c) * 8;
      gload16(&A[(size_t)(bm * 128 + rc + srow) * K + kt * 64 + scol],
              (void*)(As + rc * 64));
      gload16(&Bt[(size_t)(bn * 128 + rc + srow) * K + kt * 64 + scol],
              (void*)(Bs + rc * 64));
    }
    __syncthreads();
#pragma unroll
    for (int kk = 0; kk < 2; ++kk) {
      short8 af[4], bf[4];
#pragma unroll
      for (int m = 0; m < 4; ++m)
        af[m] = *(const short8*)(As + (wr * 64 + m * 16 + lc) * 64 + kk * 32 + grp * 8);
#pragma unroll
      for (int n = 0; n < 4; ++n)
        bf[n] = *(const short8*)(Bs + (wc * 64 + n * 16 + lc) * 64 + kk * 32 + grp * 8);
#pragma unroll
      for (int m = 0; m < 4; ++m)
#pragma unroll
        for (int n = 0; n < 4; ++n)
          acc[m][n] = __builtin_amdgcn_mfma_f32_16x16x32_bf16(af[m], bf[n], acc[m][n], 0, 0, 0);
    }
    __syncthreads();
  }

  const int gm0 = bm * 128 + wr * 64;
  const int gn0 = bn * 128 + wc * 64;
  if (MODE == 0) {
    const int seg = gn0 >> 10;
#pragma unroll
    for (int m = 0; m < 4; ++m) {
#pragma unroll
      for (int n = 0; n < 4; ++n) {
        const int gn = gn0 + n * 16 + lc;
        const float bv = bias[gn];
        const int j = gn & 1023;
        const int h = j >> 6, d = j & 63;
#pragma unroll
        for (int r = 0; r < 4; ++r) {
          const int gm = gm0 + m * 16 + grp * 4 + r;
          const int b = gm >> 11, s = gm & 2047;
          const unsigned short val = f2bf(acc[m][n][r] + bv);
          if (seg == 0)
            q_out[(((size_t)(b * NH + h)) * S_LEN + s) * DH + d] = val;
          else if (seg == 1)
            k_out[(((size_t)(b * NH + h)) * S_LEN + s) * DH + d] = val;
          else
            vt_out[(((size_t)(b * NH + h)) * DH + d) * S_LEN + s] = val;
        }
      }
    }
  } else {
#pragma unroll
    for (int m = 0; m < 4; ++m) {
#pragma unroll
      for (int n = 0; n < 4; ++n) {
        const int gn = gn0 + n * 16 + lc;
        const float bv = bias[gn];
#pragma unroll
        for (int r = 0; r < 4; ++r) {
          const int gm = gm0 + m * 16 + grp * 4 + r;
          f_out[(size_t)gm * N + gn] = acc[m][n][r] + bv;
        }
      }
    }
  }
}

// ---------------- flash attention v3 (swapped-QK^T, 32x32 MFMA) ----------------
// Q,K: [BH][S][64] bf16; Vt: [BH][64][S] bf16; Aout: [B*S][1024] bf16
// Block: 4 waves x 32 q rows; block covers q-tile pair {t, 15-t} (load balance).
// Per 64-kv block: S^T = mfma(K,Q); lane-local softmax (q = lane&31, k split
// across lane pairs l/l+32, combined via __shfl_xor(.,32)); P^T routed through
// per-wave XOR-swizzled LDS tile; O^T = mfma(Vt, P^T). No cross-wave barriers.

#define CSCALE 0.18033688011112042f  // 0.125 * log2(e)

__global__ __launch_bounds__(256, 2)
void attn_fwd3(const unsigned short* __restrict__ Q,
               const unsigned short* __restrict__ K,
               const unsigned short* __restrict__ Vt,
               unsigned short* __restrict__ Aout) {
  __shared__ __attribute__((aligned(16))) unsigned short Pl[4][32][64];
  __shared__ float olds[4][32 * 65];
  const int tid  = threadIdx.x;
  const int lane = tid & 63, w = tid >> 6;
  const int q32  = lane & 31;
  const int hi   = lane >> 5;
  const int pid  = blockIdx.x & 7;
  const int bh   = blockIdx.x >> 3;
  const int b    = bh >> 4, h = bh & 15;
  const size_t kq_base = (size_t)bh * (S_LEN * DH);
  const size_t vt_base = (size_t)bh * (DH * S_LEN);
  unsigned short* prow = &Pl[w][q32][0];
  const int swz = (q32 & 7) << 3;

#pragma unroll 1
  for (int half = 0; half < 2; ++half) {
    const int tile = half ? (15 - pid) : pid;
    const int qw0  = tile * 128 + w * 32;

    short8 qf[4];
#pragma unroll
    for (int s = 0; s < 4; ++s)
      qf[s] = *(const short8*)(Q + kq_base + (size_t)(qw0 + q32) * DH + s * 16 + hi * 8);

    f32x16 oa, ob;
#pragma unroll
    for (int rr = 0; rr < 16; ++rr) { oa[rr] = 0.f; ob[rr] = 0.f; }
    float m = -1e30f, l = 0.f;

    const int nb = ((qw0 + 31) >> 6) + 1;
#pragma unroll 1
    for (int kb = 0; kb < nb; ++kb) {
      const int kvb = kb << 6;
      short8 kf[2][4], vf[2][4];
#pragma unroll
      for (int sub = 0; sub < 2; ++sub)
#pragma unroll
        for (int s = 0; s < 4; ++s)
          kf[sub][s] = *(const short8*)(K + kq_base +
                         (size_t)(kvb + sub * 32 + q32) * DH + s * 16 + hi * 8);
#pragma unroll
      for (int dt = 0; dt < 2; ++dt)
#pragma unroll
        for (int ks = 0; ks < 4; ++ks)
          vf[dt][ks] = *(const short8*)(Vt + vt_base +
                         (size_t)(dt * 32 + q32) * S_LEN + kvb + ks * 16 + hi * 8);

      f32x16 c0, c1;
#pragma unroll
      for (int rr = 0; rr < 16; ++rr) { c0[rr] = 0.f; c1[rr] = 0.f; }
#pragma unroll
      for (int s = 0; s < 4; ++s) c0 = mfma32(kf[0][s], qf[s], c0);
#pragma unroll
      for (int s = 0; s < 4; ++s) c1 = mfma32(kf[1][s], qf[s], c1);

      if (kvb + 63 > qw0) {  // diagonal block: elementwise causal mask
        const int thr = qw0 + q32 - kvb;
#pragma unroll
        for (int rr = 0; rr < 16; ++rr) {
          const int k0 = (rr & 3) + 8 * (rr >> 2) + 4 * hi;
          if (k0 > thr)      c0[rr] = -1e30f;
          if (k0 + 32 > thr) c1[rr] = -1e30f;
        }
      }

      // lane-local max over 32 S values + cross-half combine (lane ^ 32)
      float mx = c0[0];
#pragma unroll
      for (int rr = 1; rr < 16; ++rr) mx = fmaxf(mx, c0[rr]);
#pragma unroll
      for (int rr = 0; rr < 16; ++rr) mx = fmaxf(mx, c1[rr]);
      mx = fmaxf(mx, __shfl_xor(mx, 32));
      const float mnew = fmaxf(m, mx);
      const float so = exp2f((m - mnew) * CSCALE);

      float p[32];
      float ps = 0.f;
#pragma unroll
      for (int rr = 0; rr < 16; ++rr) { p[rr] = exp2f((c0[rr] - mnew) * CSCALE); ps += p[rr]; }
#pragma unroll
      for (int rr = 0; rr < 16; ++rr) { p[16 + rr] = exp2f((c1[rr] - mnew) * CSCALE); ps += p[16 + rr]; }
      ps += __shfl_xor(ps, 32);
      l = l * so + ps;
      m = mnew;
#pragma unroll
      for (int rr = 0; rr < 16; ++rr) { oa[rr] *= so; ob[rr] *= so; }

      // write P (bf16) into per-wave swizzled LDS row [q32][k ^ swz]
#pragma unroll
      for (int rr = 0; rr < 16; rr += 4) {
        const int k0 = 8 * (rr >> 2) + 4 * hi;  // rr&3 == 0 -> 4 consecutive k
        uint2 d0, d1;
        d0.x = (uint32_t)f2bf(p[rr])      | ((uint32_t)f2bf(p[rr + 1]) << 16);
        d0.y = (uint32_t)f2bf(p[rr + 2])  | ((uint32_t)f2bf(p[rr + 3]) << 16);
        d1.x = (uint32_t)f2bf(p[16 + rr]) | ((uint32_t)f2bf(p[17 + rr]) << 16);
        d1.y = (uint32_t)f2bf(p[18 + rr]) | ((uint32_t)f2bf(p[19 + rr]) << 16);
        *(uint2*)&prow[k0 ^ swz]        = d0;
        *(uint2*)&prow[(k0 + 32) ^ swz] = d1;
      }
      asm volatile("s_waitcnt lgkmcnt(0)" ::: "memory");
      __builtin_amdgcn_sched_barrier(0);

      short8 bfr[4];
#pragma unroll
      for (int ks = 0; ks < 4; ++ks)
        bfr[ks] = *(const short8*)&prow[(ks * 16 + hi * 8) ^ swz];
#pragma unroll
      for (int ks = 0; ks < 4; ++ks) {
        oa = mfma32(vf[0][ks], bfr[ks], oa);
        ob = mfma32(vf[1][ks], bfr[ks], ob);
      }
      asm volatile("s_waitcnt lgkmcnt(0)" ::: "memory");
      __builtin_amdgcn_sched_barrier(0);
    }

    // epilogue: transpose O^T -> O through per-wave LDS, coalesced bf16 stores
    const float inv = 1.0f / l;
    float* wl = olds[w];
#pragma unroll
    for (int rr = 0; rr < 16; ++rr) {
      const int d = (rr & 3) + 8 * (rr >> 2) + 4 * hi;
      wl[q32 * 65 + d]      = oa[rr] * inv;
      wl[q32 * 65 + 32 + d] = ob[rr] * inv;
    }
    asm volatile("s_waitcnt lgkmcnt(0)" ::: "memory");
    __builtin_amdgcn_sched_barrier(0);
    const int er = lane >> 1, eh = lane & 1;
    const float* lr = &wl[er * 65 + eh * 32];
    unsigned short* op = Aout + ((size_t)(b * S_LEN + qw0 + er)) * D_EMB + h * DH + eh * 32;
#pragma unroll
    for (int j = 0; j < 32; j += 8) {
      short8 ov;
#pragma unroll
      for (int t2 = 0; t2 < 8; ++t2) ov[t2] = (short)f2bf(lr[j + t2]);
      *(short8*)(op + j) = ov;
    }
    asm volatile("s_waitcnt lgkmcnt(0)" ::: "memory");
    __builtin_amdgcn_sched_barrier(0);
  }
}

// ---------------- launcher ----------------

extern "C" void kernel_launch(void* const* d_in, const int* in_sizes, int n_in,
                              void* d_out, int out_size, void* d_ws, size_t ws_size,
                              hipStream_t stream) {
  const float* x     = (const float*)d_in[0];
  const float* W_in  = (const float*)d_in[1];
  const float* b_in  = (const float*)d_in[2];
  const float* W_out = (const float*)d_in[3];
  const float* b_out = (const float*)d_in[4];

  char* ws = (char*)d_ws;
  unsigned short* xb  = (unsigned short*)(ws);              // 16 MB: x bf16, later attn_out
  unsigned short* Wti = (unsigned short*)(ws + 16777216);   // 6 MB: W_in^T bf16 [3072][1024]
  unsigned short* Wto = (unsigned short*)(ws + 23068672);   // 2 MB: W_out^T bf16 [1024][1024]
  unsigned short* Qb  = (unsigned short*)(ws + 25165824);   // 16 MB [64][2048][64]
  unsigned short* Kb  = (unsigned short*)(ws + 41943040);   // 16 MB [64][2048][64]
  unsigned short* Vtb = (unsigned short*)(ws + 58720256);   // 16 MB [64][64][2048]
  float* out = (float*)d_out;

  cvt_bf16<<<8192, 256, 0, stream>>>(x, xb, 8388608);
  transpose_cvt<<<16 * 48, 256, 0, stream>>>(W_in, Wti, 1024, 3072);
  transpose_cvt<<<16 * 16, 256, 0, stream>>>(W_out, Wto, 1024, 1024);

  // QKV projection: M=8192, N=3072, K=1024
  gemm_bt<0><<<64 * 24, 256, 0, stream>>>(xb, Wti, b_in, Qb, Kb, Vtb, nullptr,
                                          8192, 3072, 1024);
  // causal flash attention: 64 bh x 8 balanced tile-pairs
  attn_fwd3<<<512, 256, 0, stream>>>(Qb, Kb, Vtb, xb);
  // output projection: M=8192, N=1024, K=1024 -> fp32 + b_out
  gemm_bt<1><<<64 * 8, 256, 0, stream>>>(xb, Wto, b_out, nullptr, nullptr, nullptr, out,
                                         8192, 1024, 1024);
}